// Round 5
// baseline (4114.577 us; speedup 1.0000x reference)
//
#include <hip/hip_runtime.h>
#include <hip/hip_bf16.h>
#include <math.h>

#define SEQ 512
#define BATCH 64
#define HID 1024
#define G3 3072
#define LAYERS 3
#define JW 16      // hidden dims owned per WG
#define NWGL 64    // WGs per layer group
#define HBLK 65536 // elements per h snapshot: 64 kblocks x 64 batch x 16

typedef __bf16 bf16;
typedef __bf16 bf16x8 __attribute__((ext_vector_type(8)));
typedef __bf16 bf16x4 __attribute__((ext_vector_type(4)));
typedef float f32x4 __attribute__((ext_vector_type(4)));

static __device__ inline bf16x8 cvt_bf8(f32x4 a, f32x4 b) {
  bf16x8 r;
  r[0] = (bf16)a[0]; r[1] = (bf16)a[1]; r[2] = (bf16)a[2]; r[3] = (bf16)a[3];
  r[4] = (bf16)b[0]; r[5] = (bf16)b[1]; r[6] = (bf16)b[2]; r[7] = (bf16)b[3];
  return r;
}

// x[s][b][k] (f32) -> xb[s][k>>4][b][k&15] (bf16): blocked layout matching hbuf.
__global__ __launch_bounds__(256) void x_to_bf16_blk(const float* __restrict__ x,
                                                     bf16* __restrict__ xb) {
  const int g = blockIdx.x * 256 + threadIdx.x;
  const int b = g & 63;
  const int kb = (g >> 6) & 63;
  const int s = g >> 12;
  const float* src = x + ((size_t)s * 64 + b) * 1024 + kb * 16;
  bf16* dst = xb + (size_t)s * HBLK + kb * 1024 + b * 16;
  f32x4 a0 = *(const f32x4*)(src);
  f32x4 a1 = *(const f32x4*)(src + 4);
  f32x4 a2 = *(const f32x4*)(src + 8);
  f32x4 a3 = *(const f32x4*)(src + 12);
  *(bf16x8*)(dst) = cvt_bf8(a0, a1);
  *(bf16x8*)(dst + 8) = cvt_bf8(a2, a3);
}

// coherent (bypass L1/L2) and plain 16B loads: SGPR base + 32b voffset + imm
#define GLOAD4C(dst, voff, sbase, IMM)                                        \
  asm volatile("global_load_dwordx4 %0, %1, %2 offset:" #IMM " sc0 sc1"       \
               : "=v"(dst) : "v"(voff), "s"(sbase) : "memory")
#define GLOAD4P(dst, voff, sbase, IMM)                                        \
  asm volatile("global_load_dwordx4 %0, %1, %2 offset:" #IMM                  \
               : "=v"(dst) : "v"(voff), "s"(sbase) : "memory")
#define VMWAIT(N)                                                             \
  do {                                                                        \
    asm volatile("s_waitcnt vmcnt(" #N ")" ::: "memory");                     \
    __builtin_amdgcn_sched_barrier(0);                                        \
  } while (0)

// per-wave sub-flag index (128B line each)
#define FLG(layer, wg_, wv) ((((layer) * 64 + (wg_)) * 4 + (wv)) * 32)

// R9: x-prefetch (x-phase off the critical path) + per-wave sub-flags.
// Flag protocol per wave (monotone): init=2; h-complete(s) -> 2s+4 (posted
// after own store drain, no WG barrier); x-read(s+1)-done -> 2s+5 (posted in
// prefetch after loads land). Peer wait: >=2s+2. Upstream wait (prefetch
// s+1): >=2s+6. Drain before store(s): downstream x-read tick >=2s-1.
__global__ __launch_bounds__(256, 1) void gru_persist(
    const bf16*  __restrict__ xb,    // [SEQ][64 kb][64 b][16] bf16
    const float* __restrict__ h0,    // [LAYERS][BATCH][HID]
    const float* __restrict__ wih,   // [LAYERS*G3][HID]
    const float* __restrict__ whh,   // [LAYERS*G3][HID]
    const float* __restrict__ bih,   // [LAYERS*G3]
    const float* __restrict__ bhh,   // [LAYERS*G3]
    float* __restrict__ out,         // [SEQ][BATCH][HID]
    bf16*  __restrict__ hbuf,        // [LAYERS][2][64 kb][64 b][16] bf16
    int*   __restrict__ flg)         // [LAYERS][NWGL][4 waves] x 32-int lines
{
  const int l    = blockIdx.x >> 6;
  const int wg   = blockIdx.x & 63;
  const int j0   = wg * JW;
  const int tid  = threadIdx.x;
  const int lane = tid & 63, wave = tid >> 6;
  const int quad = lane >> 4, l16 = lane & 15;
  const int kr   = wave * 256;   // this wave's K range

  // [wave][plane R,Z,GN,INa,INb][nt][col=batch%16][row j + pad]
  __shared__ __align__(16) float part[4][5][4][16][20];  // 100 KiB

  // ---- prologue: both weight slices -> register A-fragments ----
  const float* WhhL = whh + (size_t)l * G3 * HID;
  const float* WihL = wih + (size_t)l * G3 * HID;
  bf16x8 aH[3][8], aI[3][8];
#pragma unroll
  for (int g = 0; g < 3; g++) {
    const int row = g * HID + j0 + l16;
    const float* ph = WhhL + (size_t)row * HID + kr + quad * 8;
    const float* pi = WihL + (size_t)row * HID + kr + quad * 8;
#pragma unroll
    for (int t = 0; t < 8; t++) {
      f32x4 h0v = *(const f32x4*)(ph + t * 32);
      f32x4 h1v = *(const f32x4*)(ph + t * 32 + 4);
      aH[g][t] = cvt_bf8(h0v, h1v);
      f32x4 i0v = *(const f32x4*)(pi + t * 32);
      f32x4 i1v = *(const f32x4*)(pi + t * 32 + 4);
      aI[g][t] = cvt_bf8(i0v, i1v);
    }
  }

  // thread's epilogue ownership: batch bown, 4 consecutive j (jg*4..jg*4+3)
  const int bown = tid >> 2, jg = tid & 3;
  const int ntb = bown >> 4, bl = bown & 15;

  // biases in registers (uniform per thread across steps)
  const f32x4 bI0 = *(const f32x4*)(bih + l * G3 + 0 * HID + j0 + jg * 4);
  const f32x4 bI1 = *(const f32x4*)(bih + l * G3 + 1 * HID + j0 + jg * 4);
  const f32x4 bI2 = *(const f32x4*)(bih + l * G3 + 2 * HID + j0 + jg * 4);
  const f32x4 bH0 = *(const f32x4*)(bhh + l * G3 + 0 * HID + j0 + jg * 4);
  const f32x4 bH1 = *(const f32x4*)(bhh + l * G3 + 1 * HID + j0 + jg * 4);
  const f32x4 bH2 = *(const f32x4*)(bhh + l * G3 + 2 * HID + j0 + jg * 4);

  // h carry in registers (f32) + blocked hbuf parity 0 (bf16 through-L3)
  f32x4 hprev = *(const f32x4*)(h0 + ((size_t)l * BATCH + bown) * HID + j0 + jg * 4);
  {
    bf16x4 p4; p4[0] = (bf16)hprev[0]; p4[1] = (bf16)hprev[1];
    p4[2] = (bf16)hprev[2]; p4[3] = (bf16)hprev[3];
    bf16* dst = hbuf + (size_t)(l * 2) * HBLK + wg * 1024 + bown * 16 + jg * 4;
    asm volatile("global_store_dwordx2 %0, %1, off sc0 sc1"
                 :: "v"(dst), "v"(p4) : "memory");
  }
  asm volatile("s_waitcnt vmcnt(0)" ::: "memory");
  int* myflag = flg + FLG(l, wg, wave);
  if ((tid & 63) == 0)
    __hip_atomic_store(myflag, 2, __ATOMIC_RELAXED, __HIP_MEMORY_SCOPE_AGENT);

  // gather pointers: lane <-> (producer 16w+(lane&15), producer-wave lane>>4)
  const int* gpPeer = flg + FLG(l, (wave << 4) + (lane & 15), lane >> 4);
  const int* gpUp   = (l > 0) ? flg + FLG(l - 1, (wave << 4) + (lane & 15), lane >> 4) : nullptr;
  const int* gpDown = (l + 1 < LAYERS) ? flg + FLG(l + 1, lane, wg >> 4) : nullptr;

  // per-lane byte offset within an h snapshot block (blocked layout)
  const int base_lane = (wave * 16 + (quad >> 1)) * 1024 + l16 * 16 + (quad & 1) * 8;
  const unsigned base_byte = (unsigned)base_lane * 2;

  f32x4 accR[4], accZ[4], accIN[4];
  bf16x8 bv[8][4];
  int dsn = 0x7fffffff;

  // ---- pre-loop prefetch: x(0) ----
  {
#pragma unroll
    for (int nt = 0; nt < 4; nt++) {
      accR[nt] = (f32x4)(0.0f); accZ[nt] = (f32x4)(0.0f); accIN[nt] = (f32x4)(0.0f);
    }
    if (l > 0) {
      while (!__all(__hip_atomic_load(gpUp, __ATOMIC_RELAXED,
                                      __HIP_MEMORY_SCOPE_AGENT) >= 4))
        __builtin_amdgcn_s_sleep(1);
      const bf16* ibase = hbuf + (size_t)((l - 1) * 2 + 1) * HBLK;
#pragma unroll
      for (int t = 0; t < 8; t++) {
        const unsigned voff = base_byte + t * 4096;
        GLOAD4C(bv[t][0], voff, ibase, 0);
        GLOAD4C(bv[t][1], voff, ibase, 512);
        GLOAD4C(bv[t][2], voff, ibase, 1024);
        GLOAD4C(bv[t][3], voff, ibase, 1536);
      }
    } else {
      const bf16* ibase = xb;
#pragma unroll
      for (int t = 0; t < 8; t++) {
        const unsigned voff = base_byte + t * 4096;
        GLOAD4P(bv[t][0], voff, ibase, 0);
        GLOAD4P(bv[t][1], voff, ibase, 512);
        GLOAD4P(bv[t][2], voff, ibase, 1024);
        GLOAD4P(bv[t][3], voff, ibase, 1536);
      }
    }
    if (l + 1 < LAYERS)
      asm volatile("global_load_dword %0, %1, off sc0 sc1"
                   : "=v"(dsn) : "v"(gpDown) : "memory");
    VMWAIT(0);
    if ((tid & 63) == 0)
      __hip_atomic_store(myflag, 3, __ATOMIC_RELAXED, __HIP_MEMORY_SCOPE_AGENT);
#pragma unroll
    for (int t = 0; t < 8; t++)
#pragma unroll
      for (int nt = 0; nt < 4; nt++) {
        accR[nt]  = __builtin_amdgcn_mfma_f32_16x16x32_bf16(aI[0][t], bv[t][nt], accR[nt], 0, 0, 0);
        accZ[nt]  = __builtin_amdgcn_mfma_f32_16x16x32_bf16(aI[1][t], bv[t][nt], accZ[nt], 0, 0, 0);
        accIN[nt] = __builtin_amdgcn_mfma_f32_16x16x32_bf16(aI[2][t], bv[t][nt], accIN[nt], 0, 0, 0);
      }
#pragma unroll
    for (int nt = 0; nt < 4; nt++)
      *(f32x4*)&part[wave][3][nt][l16][quad * 4] = accIN[nt];
  }

  for (int s = 0; s < SEQ; s++) {
    // ---- 1. peer wait: all peer waves completed step s-1 ----
    {
      const int tgt = 2 * s + 2;
      while (!__all(__hip_atomic_load(gpPeer, __ATOMIC_RELAXED,
                                      __HIP_MEMORY_SCOPE_AGENT) >= tgt))
        __builtin_amdgcn_s_sleep(1);
    }

    // ---- 2. h loads + h-MFMA (R,Z accumulate onto prefetched x; GN fresh) ----
    f32x4 accGN[4];
#pragma unroll
    for (int nt = 0; nt < 4; nt++) accGN[nt] = (f32x4)(0.0f);
    const bf16* hbase = hbuf + (size_t)(l * 2 + (s & 1)) * HBLK;
#pragma unroll
    for (int t = 0; t < 8; t++) {
      const unsigned voff = base_byte + t * 4096;
      GLOAD4C(bv[t][0], voff, hbase, 0);
      GLOAD4C(bv[t][1], voff, hbase, 512);
      GLOAD4C(bv[t][2], voff, hbase, 1024);
      GLOAD4C(bv[t][3], voff, hbase, 1536);
    }
#define HMFMA2(T0, T1)                                                        \
  for (int t = T0; t <= T1; t++)                                              \
    for (int nt = 0; nt < 4; nt++) {                                          \
      accR[nt]  = __builtin_amdgcn_mfma_f32_16x16x32_bf16(aH[0][t], bv[t][nt], accR[nt], 0, 0, 0);  \
      accZ[nt]  = __builtin_amdgcn_mfma_f32_16x16x32_bf16(aH[1][t], bv[t][nt], accZ[nt], 0, 0, 0);  \
      accGN[nt] = __builtin_amdgcn_mfma_f32_16x16x32_bf16(aH[2][t], bv[t][nt], accGN[nt], 0, 0, 0); \
    }
    VMWAIT(24); HMFMA2(0, 1)
    VMWAIT(16); HMFMA2(2, 3)
    VMWAIT(8);  HMFMA2(4, 5)
    VMWAIT(0);  HMFMA2(6, 7)
#undef HMFMA2

    // ---- 3. park R,Z,GN partials ----
#pragma unroll
    for (int nt = 0; nt < 4; nt++) {
      *(f32x4*)&part[wave][0][nt][l16][quad * 4] = accR[nt];
      *(f32x4*)&part[wave][1][nt][l16][quad * 4] = accZ[nt];
      *(f32x4*)&part[wave][2][nt][l16][quad * 4] = accGN[nt];
    }
    __syncthreads();  // barrier A: all partials visible

    // ---- 4. cross-wave reduce (planes 0,1,2 and IN parity 3+(s&1)) ----
    const int pIN = 3 + (s & 1);
    f32x4 sR, sZ, sGN, sIN;
    {
      sR  = *(const f32x4*)&part[0][0][ntb][bl][jg * 4];
      sZ  = *(const f32x4*)&part[0][1][ntb][bl][jg * 4];
      sGN = *(const f32x4*)&part[0][2][ntb][bl][jg * 4];
      sIN = *(const f32x4*)&part[0][pIN][ntb][bl][jg * 4];
#pragma unroll
      for (int w = 1; w < 4; w++) {
        sR  += *(const f32x4*)&part[w][0][ntb][bl][jg * 4];
        sZ  += *(const f32x4*)&part[w][1][ntb][bl][jg * 4];
        sGN += *(const f32x4*)&part[w][2][ntb][bl][jg * 4];
        sIN += *(const f32x4*)&part[w][pIN][ntb][bl][jg * 4];
      }
    }
    __syncthreads();  // barrier B: reads done before next-phase part writes

    // ---- 5. epilogue ----
    f32x4 hn;
#pragma unroll
    for (int c = 0; c < 4; c++) {
      const float r = __fdividef(1.f, 1.f + __expf(-(sR[c] + bI0[c] + bH0[c])));
      const float z = __fdividef(1.f, 1.f + __expf(-(sZ[c] + bI1[c] + bH1[c])));
      const float a = sIN[c] + bI2[c] + r * (sGN[c] + bH2[c]);
      const float e2 = __expf(2.f * a);
      const float n = 1.f - __fdividef(2.f, e2 + 1.f);
      hn[c] = (1.f - z) * n + z * hprev[c];
    }
    hprev = hn;

    // ---- 6. drain: downstream x-read of h(s-2) done (tick 2s-1) ----
    if (l + 1 < LAYERS && !__all(dsn >= 2 * s - 1)) {
      const int tgt = 2 * s - 1;
      while (!__all(__hip_atomic_load(gpDown, __ATOMIC_RELAXED,
                                      __HIP_MEMORY_SCOPE_AGENT) >= tgt))
        __builtin_amdgcn_s_sleep(1);
    }

    // ---- 7. h store; per-wave drain; per-wave flag post ----
    {
      bf16x4 p4; p4[0] = (bf16)hn[0]; p4[1] = (bf16)hn[1];
      p4[2] = (bf16)hn[2]; p4[3] = (bf16)hn[3];
      bf16* dst = hbuf + (size_t)(l * 2 + ((s + 1) & 1)) * HBLK
                  + wg * 1024 + bown * 16 + jg * 4;
      asm volatile("global_store_dwordx2 %0, %1, off sc0 sc1"
                   :: "v"(dst), "v"(p4) : "memory");
    }
    asm volatile("s_waitcnt vmcnt(0)" ::: "memory");
    if ((tid & 63) == 0)
      __hip_atomic_store(myflag, 2 * s + 4,
                         __ATOMIC_RELAXED, __HIP_MEMORY_SCOPE_AGENT);
    if (l == 2)  // plain cached store; visible at kernel end
      *(f32x4*)(out + ((size_t)s * BATCH + bown) * HID + j0 + jg * 4) = hn;

    // ---- 8. prefetch x(s+1) while peers finish ----
    if (s + 1 < SEQ) {
#pragma unroll
      for (int nt = 0; nt < 4; nt++) {
        accR[nt] = (f32x4)(0.0f); accZ[nt] = (f32x4)(0.0f); accIN[nt] = (f32x4)(0.0f);
      }
      if (l > 0) {
        const int tgt = 2 * s + 6;  // upstream h-complete(s+1)
        while (!__all(__hip_atomic_load(gpUp, __ATOMIC_RELAXED,
                                        __HIP_MEMORY_SCOPE_AGENT) >= tgt))
          __builtin_amdgcn_s_sleep(1);
        const bf16* ibase = hbuf + (size_t)((l - 1) * 2 + (s & 1)) * HBLK;
#pragma unroll
        for (int t = 0; t < 8; t++) {
          const unsigned voff = base_byte + t * 4096;
          GLOAD4C(bv[t][0], voff, ibase, 0);
          GLOAD4C(bv[t][1], voff, ibase, 512);
          GLOAD4C(bv[t][2], voff, ibase, 1024);
          GLOAD4C(bv[t][3], voff, ibase, 1536);
        }
      } else {
        const bf16* ibase = xb + (size_t)(s + 1) * HBLK;
#pragma unroll
        for (int t = 0; t < 8; t++) {
          const unsigned voff = base_byte + t * 4096;
          GLOAD4P(bv[t][0], voff, ibase, 0);
          GLOAD4P(bv[t][1], voff, ibase, 512);
          GLOAD4P(bv[t][2], voff, ibase, 1024);
          GLOAD4P(bv[t][3], voff, ibase, 1536);
        }
      }
      if (l + 1 < LAYERS)
        asm volatile("global_load_dword %0, %1, off sc0 sc1"
                     : "=v"(dsn) : "v"(gpDown) : "memory");
      VMWAIT(0);
      if ((tid & 63) == 0)  // x-read(s+1) done
        __hip_atomic_store(myflag, 2 * s + 5,
                           __ATOMIC_RELAXED, __HIP_MEMORY_SCOPE_AGENT);
#pragma unroll
      for (int t = 0; t < 8; t++)
#pragma unroll
        for (int nt = 0; nt < 4; nt++) {
          accR[nt]  = __builtin_amdgcn_mfma_f32_16x16x32_bf16(aI[0][t], bv[t][nt], accR[nt], 0, 0, 0);
          accZ[nt]  = __builtin_amdgcn_mfma_f32_16x16x32_bf16(aI[1][t], bv[t][nt], accZ[nt], 0, 0, 0);
          accIN[nt] = __builtin_amdgcn_mfma_f32_16x16x32_bf16(aI[2][t], bv[t][nt], accIN[nt], 0, 0, 0);
        }
      // park IN(s+1) into the other parity plane (safe: past barrier B)
#pragma unroll
      for (int nt = 0; nt < 4; nt++)
        *(f32x4*)&part[wave][3 + ((s + 1) & 1)][nt][l16][quad * 4] = accIN[nt];
    }
  }
}

extern "C" void kernel_launch(void* const* d_in, const int* in_sizes, int n_in,
                              void* d_out, int out_size, void* d_ws, size_t ws_size,
                              hipStream_t stream) {
  const float* x   = (const float*)d_in[0];
  const float* h0  = (const float*)d_in[1];
  const float* wih = (const float*)d_in[2];
  const float* whh = (const float*)d_in[3];
  const float* bih = (const float*)d_in[4];
  const float* bhh = (const float*)d_in[5];
  float* out = (float*)d_out;

  char* ws = (char*)d_ws;
  size_t off = 0;
  bf16* xb   = (bf16*)(ws + off); off += (size_t)SEQ * BATCH * HID * sizeof(bf16);   // 67 MB
  bf16* hbuf = (bf16*)(ws + off); off += (size_t)LAYERS * 2 * HBLK * sizeof(bf16);   // 768 KB
  int* flg   = (int*)(ws + off);  off += LAYERS * NWGL * 4 * 32 * sizeof(int);       // 96 KB

  hipMemsetAsync(flg, 0, LAYERS * NWGL * 4 * 32 * sizeof(int), stream);
  x_to_bf16_blk<<<(SEQ * 64 * 64) / 256, 256, 0, stream>>>(x, xb);
  gru_persist<<<LAYERS * NWGL, 256, 0, stream>>>(xb, h0, wih, whh, bih, bhh,
                                                 out, hbuf, flg);
}

// Round 6
// 3836.804 us; speedup vs baseline: 1.0724x; 1.0724x over previous
//
#include <hip/hip_runtime.h>
#include <hip/hip_bf16.h>
#include <math.h>

#define SEQ 512
#define BATCH 64
#define HID 1024
#define G3 3072
#define LAYERS 3
#define JW 16      // hidden dims owned per WG
#define NWGL 64    // WGs per layer group
#define HBLK 65536 // elements per h snapshot: 64 kblocks x 64 batch x 16

typedef __bf16 bf16;
typedef __bf16 bf16x8 __attribute__((ext_vector_type(8)));
typedef __bf16 bf16x4 __attribute__((ext_vector_type(4)));
typedef float f32x4 __attribute__((ext_vector_type(4)));

static __device__ inline bf16x8 cvt_bf8(f32x4 a, f32x4 b) {
  bf16x8 r;
  r[0] = (bf16)a[0]; r[1] = (bf16)a[1]; r[2] = (bf16)a[2]; r[3] = (bf16)a[3];
  r[4] = (bf16)b[0]; r[5] = (bf16)b[1]; r[6] = (bf16)b[2]; r[7] = (bf16)b[3];
  return r;
}

// x[s][b][k] (f32) -> xb[s][k>>4][b][k&15] (bf16): blocked layout matching hbuf.
__global__ __launch_bounds__(256) void x_to_bf16_blk(const float* __restrict__ x,
                                                     bf16* __restrict__ xb) {
  const int g = blockIdx.x * 256 + threadIdx.x;
  const int b = g & 63;
  const int kb = (g >> 6) & 63;
  const int s = g >> 12;
  const float* src = x + ((size_t)s * 64 + b) * 1024 + kb * 16;
  bf16* dst = xb + (size_t)s * HBLK + kb * 1024 + b * 16;
  f32x4 a0 = *(const f32x4*)(src);
  f32x4 a1 = *(const f32x4*)(src + 4);
  f32x4 a2 = *(const f32x4*)(src + 8);
  f32x4 a3 = *(const f32x4*)(src + 12);
  *(bf16x8*)(dst) = cvt_bf8(a0, a1);
  *(bf16x8*)(dst + 8) = cvt_bf8(a2, a3);
}

// coherent (bypass L1/L2) and plain 16B loads: SGPR base + 32b voffset + imm
#define GLOAD4C(dst, voff, sbase, IMM)                                        \
  asm volatile("global_load_dwordx4 %0, %1, %2 offset:" #IMM " sc0 sc1"       \
               : "=v"(dst) : "v"(voff), "s"(sbase) : "memory")
#define GLOAD4P(dst, voff, sbase, IMM)                                        \
  asm volatile("global_load_dwordx4 %0, %1, %2 offset:" #IMM                  \
               : "=v"(dst) : "v"(voff), "s"(sbase) : "memory")
#define VMWAIT(N)                                                             \
  do {                                                                        \
    asm volatile("s_waitcnt vmcnt(" #N ")" ::: "memory");                     \
    __builtin_amdgcn_sched_barrier(0);                                        \
  } while (0)

// per-wave sub-flag index (128B line each)
#define FLG(layer, wg_, wv) ((((layer) * 64 + (wg_)) * 4 + (wv)) * 32)

// R10: R8 register discipline + R9 2-tick flags + x-latency hidden under the
// peer handshake. Per-wave monotone flag: init 2; x-done(s)=2s+3 (posted after
// peer-poll drains the x loads into regs); h-done(s)=2s+4 (after store drain).
// Waits at step s: upstream h-done(s) >= 2s+4 (snapshot+fallback);
// peers h-done(s-1) >= 2s+2 (blocking poll, overlaps x-load latency);
// drain: downstream x-done(s-2) >= 2s-1 (snapshot+fallback).
__global__ __launch_bounds__(256, 1) void gru_persist(
    const bf16*  __restrict__ xb,    // [SEQ][64 kb][64 b][16] bf16
    const float* __restrict__ h0,    // [LAYERS][BATCH][HID]
    const float* __restrict__ wih,   // [LAYERS*G3][HID]
    const float* __restrict__ whh,   // [LAYERS*G3][HID]
    const float* __restrict__ bih,   // [LAYERS*G3]
    const float* __restrict__ bhh,   // [LAYERS*G3]
    float* __restrict__ out,         // [SEQ][BATCH][HID]
    bf16*  __restrict__ hbuf,        // [LAYERS][2][64 kb][64 b][16] bf16
    int*   __restrict__ flg)         // [LAYERS][NWGL][4] x 32-int lines
{
  const int l    = blockIdx.x >> 6;
  const int wg   = blockIdx.x & 63;
  const int j0   = wg * JW;
  const int tid  = threadIdx.x;
  const int lane = tid & 63, wave = tid >> 6;
  const int quad = lane >> 4, l16 = lane & 15;
  const int kr   = wave * 256;   // this wave's K range

  // [wave][gate R,Z,GN,IN][nt][col=batch%16][row j + pad] -> b128 LDS ops
  __shared__ __align__(16) float part[4][4][4][16][20];  // 80 KiB

  // ---- prologue: both weight slices -> register A-fragments ----
  const float* WhhL = whh + (size_t)l * G3 * HID;
  const float* WihL = wih + (size_t)l * G3 * HID;
  bf16x8 aH[3][8], aI[3][8];
#pragma unroll
  for (int g = 0; g < 3; g++) {
    const int row = g * HID + j0 + l16;
    const float* ph = WhhL + (size_t)row * HID + kr + quad * 8;
    const float* pi = WihL + (size_t)row * HID + kr + quad * 8;
#pragma unroll
    for (int t = 0; t < 8; t++) {
      f32x4 h0v = *(const f32x4*)(ph + t * 32);
      f32x4 h1v = *(const f32x4*)(ph + t * 32 + 4);
      aH[g][t] = cvt_bf8(h0v, h1v);
      f32x4 i0v = *(const f32x4*)(pi + t * 32);
      f32x4 i1v = *(const f32x4*)(pi + t * 32 + 4);
      aI[g][t] = cvt_bf8(i0v, i1v);
    }
  }

  // thread's epilogue ownership: batch bown, 4 consecutive j (jg*4..jg*4+3)
  const int bown = tid >> 2, jg = tid & 3;
  const int ntb = bown >> 4, bl = bown & 15;

  // biases in registers (uniform per thread across steps)
  const f32x4 bI0 = *(const f32x4*)(bih + l * G3 + 0 * HID + j0 + jg * 4);
  const f32x4 bI1 = *(const f32x4*)(bih + l * G3 + 1 * HID + j0 + jg * 4);
  const f32x4 bI2 = *(const f32x4*)(bih + l * G3 + 2 * HID + j0 + jg * 4);
  const f32x4 bH0 = *(const f32x4*)(bhh + l * G3 + 0 * HID + j0 + jg * 4);
  const f32x4 bH1 = *(const f32x4*)(bhh + l * G3 + 1 * HID + j0 + jg * 4);
  const f32x4 bH2 = *(const f32x4*)(bhh + l * G3 + 2 * HID + j0 + jg * 4);

  // h carry in registers (f32) + blocked hbuf parity 0 (bf16 through-L3)
  f32x4 hprev = *(const f32x4*)(h0 + ((size_t)l * BATCH + bown) * HID + j0 + jg * 4);
  {
    bf16x4 p4; p4[0] = (bf16)hprev[0]; p4[1] = (bf16)hprev[1];
    p4[2] = (bf16)hprev[2]; p4[3] = (bf16)hprev[3];
    bf16* dst = hbuf + (size_t)(l * 2) * HBLK + wg * 1024 + bown * 16 + jg * 4;
    asm volatile("global_store_dwordx2 %0, %1, off sc0 sc1"
                 :: "v"(dst), "v"(p4) : "memory");
  }
  asm volatile("s_waitcnt vmcnt(0)" ::: "memory");
  int* myflag = flg + FLG(l, wg, wave);
  if ((tid & 63) == 0)
    __hip_atomic_store(myflag, 2, __ATOMIC_RELAXED, __HIP_MEMORY_SCOPE_AGENT);

  // gather pointers: lane <-> (producer WG, producer wave)
  const int* gpPeer = flg + FLG(l, (wave << 4) + (lane & 15), lane >> 4);
  const int* gpUp   = (l > 0) ? flg + FLG(l - 1, (wave << 4) + (lane & 15), lane >> 4) : nullptr;
  const int* gpDown = (l + 1 < LAYERS) ? flg + FLG(l + 1, lane, wg >> 4) : nullptr;

  // per-lane byte offset within an h snapshot block (blocked layout)
  const int base_lane = (wave * 16 + (quad >> 1)) * 1024 + l16 * 16 + (quad & 1) * 8;
  const unsigned base_byte = (unsigned)base_lane * 2;

  int usn = 0;            // upstream snapshot (refreshed each step)
  int dsn = 0x7fffffff;   // downstream x-done snapshot

  for (int s = 0; s < SEQ; s++) {
    // ---- 1. upstream gate for x(s): h-done(s) = 2s+4 ----
    if (l > 0) {
      const int tgt = 2 * s + 4;
      if (!__all(usn >= tgt)) {
        while (!__all(__hip_atomic_load(gpUp, __ATOMIC_RELAXED,
                                        __HIP_MEMORY_SCOPE_AGENT) >= tgt))
          __builtin_amdgcn_s_sleep(1);
      }
    }

    // ---- 2. x-issue (32 loads) ----
    bf16x8 bv[8][4];
    const bf16* ibase = (l > 0)
        ? (hbuf + (size_t)((l - 1) * 2 + ((s + 1) & 1)) * HBLK)
        : (xb + (size_t)s * HBLK);
    if (l > 0) {
#pragma unroll
      for (int t = 0; t < 8; t++) {
        const unsigned voff = base_byte + t * 4096;
        GLOAD4C(bv[t][0], voff, ibase, 0);
        GLOAD4C(bv[t][1], voff, ibase, 512);
        GLOAD4C(bv[t][2], voff, ibase, 1024);
        GLOAD4C(bv[t][3], voff, ibase, 1536);
      }
    } else {
#pragma unroll
      for (int t = 0; t < 8; t++) {
        const unsigned voff = base_byte + t * 4096;
        GLOAD4P(bv[t][0], voff, ibase, 0);
        GLOAD4P(bv[t][1], voff, ibase, 512);
        GLOAD4P(bv[t][2], voff, ibase, 1024);
        GLOAD4P(bv[t][3], voff, ibase, 1536);
      }
    }

    // ---- 3. peer poll (overlaps x-load latency; poll load drains vmcnt) ----
    {
      const int tgt = 2 * s + 2;
      while (!__all(__hip_atomic_load(gpPeer, __ATOMIC_RELAXED,
                                      __HIP_MEMORY_SCOPE_AGENT) >= tgt))
        __builtin_amdgcn_s_sleep(1);
    }
    VMWAIT(0);  // x data certainly in regs (usually already drained by poll)

    // ---- 4. post x-done: upstream may overwrite its slot now ----
    if ((tid & 63) == 0)
      __hip_atomic_store(myflag, 2 * s + 3,
                         __ATOMIC_RELAXED, __HIP_MEMORY_SCOPE_AGENT);

    // ---- 5. x-MFMA (R, Z, IN from zero) ----
    f32x4 accR[4], accZ[4], accGN[4], accIN[4];
#pragma unroll
    for (int nt = 0; nt < 4; nt++) {
      accR[nt] = (f32x4)(0.0f); accZ[nt] = (f32x4)(0.0f);
      accGN[nt] = (f32x4)(0.0f); accIN[nt] = (f32x4)(0.0f);
    }
#pragma unroll
    for (int t = 0; t < 8; t++)
#pragma unroll
      for (int nt = 0; nt < 4; nt++) {
        accR[nt]  = __builtin_amdgcn_mfma_f32_16x16x32_bf16(aI[0][t], bv[t][nt], accR[nt], 0, 0, 0);
        accZ[nt]  = __builtin_amdgcn_mfma_f32_16x16x32_bf16(aI[1][t], bv[t][nt], accZ[nt], 0, 0, 0);
        accIN[nt] = __builtin_amdgcn_mfma_f32_16x16x32_bf16(aI[2][t], bv[t][nt], accIN[nt], 0, 0, 0);
      }
    // park IN (x-only gate) now; plane reads of step s-1 are sealed by bar B
#pragma unroll
    for (int nt = 0; nt < 4; nt++)
      *(f32x4*)&part[wave][3][nt][l16][quad * 4] = accIN[nt];

    // ---- 6. h-issue (bv reuse) + counted-wait h-MFMA (R, Z, GN) ----
    const bf16* hbase = hbuf + (size_t)(l * 2 + (s & 1)) * HBLK;
#pragma unroll
    for (int t = 0; t < 8; t++) {
      const unsigned voff = base_byte + t * 4096;
      GLOAD4C(bv[t][0], voff, hbase, 0);
      GLOAD4C(bv[t][1], voff, hbase, 512);
      GLOAD4C(bv[t][2], voff, hbase, 1024);
      GLOAD4C(bv[t][3], voff, hbase, 1536);
    }
#define HMFMA2(T0, T1)                                                        \
  for (int t = T0; t <= T1; t++)                                              \
    for (int nt = 0; nt < 4; nt++) {                                          \
      accR[nt]  = __builtin_amdgcn_mfma_f32_16x16x32_bf16(aH[0][t], bv[t][nt], accR[nt], 0, 0, 0);  \
      accZ[nt]  = __builtin_amdgcn_mfma_f32_16x16x32_bf16(aH[1][t], bv[t][nt], accZ[nt], 0, 0, 0);  \
      accGN[nt] = __builtin_amdgcn_mfma_f32_16x16x32_bf16(aH[2][t], bv[t][nt], accGN[nt], 0, 0, 0); \
    }
    VMWAIT(24); HMFMA2(0, 1)
    VMWAIT(16); HMFMA2(2, 3)
    VMWAIT(8);  HMFMA2(4, 5)
    VMWAIT(0);  HMFMA2(6, 7)
#undef HMFMA2

    // ---- 7. refresh snapshots for this step's drain + next step's gate ----
    if (l + 1 < LAYERS)
      asm volatile("global_load_dword %0, %1, off sc0 sc1"
                   : "=v"(dsn) : "v"(gpDown) : "memory");
    if (l > 0)
      asm volatile("global_load_dword %0, %1, off sc0 sc1"
                   : "=v"(usn) : "v"(gpUp) : "memory");

    // ---- 8. park R,Z,GN; reduce; epilogue ----
#pragma unroll
    for (int nt = 0; nt < 4; nt++) {
      *(f32x4*)&part[wave][0][nt][l16][quad * 4] = accR[nt];
      *(f32x4*)&part[wave][1][nt][l16][quad * 4] = accZ[nt];
      *(f32x4*)&part[wave][2][nt][l16][quad * 4] = accGN[nt];
    }
    __syncthreads();  // bar A

    f32x4 sR, sZ, sGN, sIN;
    sR  = *(const f32x4*)&part[0][0][ntb][bl][jg * 4];
    sZ  = *(const f32x4*)&part[0][1][ntb][bl][jg * 4];
    sGN = *(const f32x4*)&part[0][2][ntb][bl][jg * 4];
    sIN = *(const f32x4*)&part[0][3][ntb][bl][jg * 4];
#pragma unroll
    for (int w = 1; w < 4; w++) {
      sR  += *(const f32x4*)&part[w][0][ntb][bl][jg * 4];
      sZ  += *(const f32x4*)&part[w][1][ntb][bl][jg * 4];
      sGN += *(const f32x4*)&part[w][2][ntb][bl][jg * 4];
      sIN += *(const f32x4*)&part[w][3][ntb][bl][jg * 4];
    }
    __syncthreads();  // bar B: reads sealed before next step's park

    f32x4 hn;
#pragma unroll
    for (int c = 0; c < 4; c++) {
      const float r = __fdividef(1.f, 1.f + __expf(-(sR[c] + bI0[c] + bH0[c])));
      const float z = __fdividef(1.f, 1.f + __expf(-(sZ[c] + bI1[c] + bH1[c])));
      const float a = sIN[c] + bI2[c] + r * (sGN[c] + bH2[c]);
      const float e2 = __expf(2.f * a);
      const float n = 1.f - __fdividef(2.f, e2 + 1.f);
      hn[c] = (1.f - z) * n + z * hprev[c];
    }
    hprev = hn;

    // ---- 9. drain: downstream x-done(s-2) >= 2s-1 ----
    if (l + 1 < LAYERS && !__all(dsn >= 2 * s - 1)) {
      const int tgt = 2 * s - 1;
      while (!__all(__hip_atomic_load(gpDown, __ATOMIC_RELAXED,
                                      __HIP_MEMORY_SCOPE_AGENT) >= tgt))
        __builtin_amdgcn_s_sleep(1);
    }

    // ---- 10. h store; per-wave drain; per-wave h-done post; out store ----
    {
      bf16x4 p4; p4[0] = (bf16)hn[0]; p4[1] = (bf16)hn[1];
      p4[2] = (bf16)hn[2]; p4[3] = (bf16)hn[3];
      bf16* dst = hbuf + (size_t)(l * 2 + ((s + 1) & 1)) * HBLK
                  + wg * 1024 + bown * 16 + jg * 4;
      asm volatile("global_store_dwordx2 %0, %1, off sc0 sc1"
                   :: "v"(dst), "v"(p4) : "memory");
    }
    asm volatile("s_waitcnt vmcnt(0)" ::: "memory");  // h at L3 (also snapshots)
    if ((tid & 63) == 0)
      __hip_atomic_store(myflag, 2 * s + 4,
                         __ATOMIC_RELAXED, __HIP_MEMORY_SCOPE_AGENT);
    if (l == 2)  // plain cached store; visible at kernel end
      *(f32x4*)(out + ((size_t)s * BATCH + bown) * HID + j0 + jg * 4) = hn;
  }
}

extern "C" void kernel_launch(void* const* d_in, const int* in_sizes, int n_in,
                              void* d_out, int out_size, void* d_ws, size_t ws_size,
                              hipStream_t stream) {
  const float* x   = (const float*)d_in[0];
  const float* h0  = (const float*)d_in[1];
  const float* wih = (const float*)d_in[2];
  const float* whh = (const float*)d_in[3];
  const float* bih = (const float*)d_in[4];
  const float* bhh = (const float*)d_in[5];
  float* out = (float*)d_out;

  char* ws = (char*)d_ws;
  size_t off = 0;
  bf16* xb   = (bf16*)(ws + off); off += (size_t)SEQ * BATCH * HID * sizeof(bf16);   // 67 MB
  bf16* hbuf = (bf16*)(ws + off); off += (size_t)LAYERS * 2 * HBLK * sizeof(bf16);   // 768 KB
  int* flg   = (int*)(ws + off);  off += LAYERS * NWGL * 4 * 32 * sizeof(int);       // 96 KB

  hipMemsetAsync(flg, 0, LAYERS * NWGL * 4 * 32 * sizeof(int), stream);
  x_to_bf16_blk<<<(SEQ * 64 * 64) / 256, 256, 0, stream>>>(x, xb);
  gru_persist<<<LAYERS * NWGL, 256, 0, stream>>>(xb, h0, wih, whh, bih, bhh,
                                                 out, hbuf, flg);
}